// Round 1
// baseline (259.624 us; speedup 1.0000x reference)
//
#include <hip/hip_runtime.h>
#include <math.h>

#define NKNOTS 10
#define RED_BLOCKS 1024
#define RED_THREADS 256
#define EVAL_BLOCKS 4096
#define EVAL_THREADS 256

// ws float layout:
//   [0]      xb1  (raw-x boundary equivalent to xn >= t[4])
//   [1]      xb2  (raw-x boundary equivalent to xn >= t[5])
//   [4..76)  72 composed cubic coeffs: [iv][basis j][k], k ascending powers of raw x
//   [128..128+RED_BLOCKS)               block mins
//   [128+RED_BLOCKS..128+2*RED_BLOCKS)  block maxs

__global__ void reduce_minmax_kernel(const float* __restrict__ x, int n,
                                     float* __restrict__ bmin,
                                     float* __restrict__ bmax) {
    float lmin = INFINITY, lmax = -INFINITY;
    int tid = blockIdx.x * blockDim.x + threadIdx.x;
    int stride = gridDim.x * blockDim.x;
    int n4 = n >> 2;
    const float4* x4 = reinterpret_cast<const float4*>(x);
    for (int i = tid; i < n4; i += stride) {
        float4 v = x4[i];
        lmin = fminf(lmin, fminf(fminf(v.x, v.y), fminf(v.z, v.w)));
        lmax = fmaxf(lmax, fmaxf(fmaxf(v.x, v.y), fmaxf(v.z, v.w)));
    }
    for (int i = (n4 << 2) + tid; i < n; i += stride) {
        float v = x[i];
        lmin = fminf(lmin, v);
        lmax = fmaxf(lmax, v);
    }
#pragma unroll
    for (int off = 32; off > 0; off >>= 1) {
        lmin = fminf(lmin, __shfl_down(lmin, off));
        lmax = fmaxf(lmax, __shfl_down(lmax, off));
    }
    __shared__ float smin[RED_THREADS / 64], smax[RED_THREADS / 64];
    int wave = threadIdx.x >> 6;
    if ((threadIdx.x & 63) == 0) { smin[wave] = lmin; smax[wave] = lmax; }
    __syncthreads();
    if (threadIdx.x == 0) {
        float m = smin[0], M = smax[0];
#pragma unroll
        for (int w = 1; w < RED_THREADS / 64; ++w) {
            m = fminf(m, smin[w]);
            M = fmaxf(M, smax[w]);
        }
        bmin[blockIdx.x] = m;
        bmax[blockIdx.x] = M;
    }
}

// Symbolically runs Cox-de Boor per non-degenerate interval, producing the 6
// basis cubics with the affine normalization xn = (x - xmin)/denom composed in.
__global__ void finalize_kernel(const float* __restrict__ bmin,
                                const float* __restrict__ bmax, int nb,
                                const float* __restrict__ knots,
                                float* __restrict__ params) {
    float lmin = INFINITY, lmax = -INFINITY;
    for (int i = threadIdx.x; i < nb; i += blockDim.x) {
        lmin = fminf(lmin, bmin[i]);
        lmax = fmaxf(lmax, bmax[i]);
    }
#pragma unroll
    for (int off = 32; off > 0; off >>= 1) {
        lmin = fminf(lmin, __shfl_down(lmin, off));
        lmax = fmaxf(lmax, __shfl_down(lmax, off));
    }
    __shared__ float smin[4], smax[4];
    int wave = threadIdx.x >> 6;
    if ((threadIdx.x & 63) == 0) { smin[wave] = lmin; smax[wave] = lmax; }
    __syncthreads();
    if (threadIdx.x == 0) {
        float m = smin[0], M = smax[0];
#pragma unroll
        for (int w = 1; w < 4; ++w) {
            m = fminf(m, smin[w]);
            M = fmaxf(M, smax[w]);
        }
        float denom_f = M - m + 1e-8f;   // f32 to match reference normalization
        double s = 1.0 / (double)denom_f;
        double bb = -(double)m * s;      // xn = s*x + bb
        double t[NKNOTS];
#pragma unroll
        for (int j = 0; j < NKNOTS; ++j) t[j] = (double)knots[j];

        // interval boundaries mapped back to raw x space
        params[0] = (float)((double)m + t[4] * (double)denom_f);
        params[1] = (float)((double)m + t[5] * (double)denom_f);

        for (int iv = 0; iv < 3; ++iv) {
            // B[j][k]: coeff of xn^k for basis level-d entry j
            double B[9][4];
            for (int j = 0; j < 9; ++j)
                for (int k = 0; k < 4; ++k) B[j][k] = 0.0;
            B[3 + iv][0] = 1.0;  // indicator of elementary interval [t[3+iv], t[4+iv])
            for (int d = 1; d <= 3; ++d) {
                for (int j = 0; j + d <= 8; ++j) {
                    double den1 = t[j + d] - t[j];
                    double den2 = t[j + d + 1] - t[j + 1];
                    double i1 = (den1 > 0.0) ? 1.0 / den1 : 0.0;
                    double i2 = (den2 > 0.0) ? 1.0 / den2 : 0.0;
                    // new B[j] = (xn - t[j])*i1*B[j] + (t[j+d+1] - xn)*i2*B[j+1]
                    double a1 = -t[j] * i1, b1 = i1;
                    double a2 = t[j + d + 1] * i2, b2 = -i2;
                    double nb0 = a1 * B[j][0] + a2 * B[j + 1][0];
                    double nb1 = a1 * B[j][1] + b1 * B[j][0] + a2 * B[j + 1][1] + b2 * B[j + 1][0];
                    double nb2 = a1 * B[j][2] + b1 * B[j][1] + a2 * B[j + 1][2] + b2 * B[j + 1][1];
                    double nb3 = a1 * B[j][3] + b1 * B[j][2] + a2 * B[j + 1][3] + b2 * B[j + 1][2];
                    B[j][0] = nb0; B[j][1] = nb1; B[j][2] = nb2; B[j][3] = nb3;
                }
            }
            // compose with xn = s*x + bb:  q(x) = P(s*x + bb) via symbolic Horner
            for (int j = 0; j < 6; ++j) {
                double q0 = B[j][3], q1 = 0.0, q2 = 0.0, q3 = 0.0;
                for (int k = 2; k >= 0; --k) {
                    double r0 = q0 * bb + B[j][k];
                    double r1 = q1 * bb + q0 * s;
                    double r2 = q2 * bb + q1 * s;
                    double r3 = q3 * bb + q2 * s;
                    q0 = r0; q1 = r1; q2 = r2; q3 = r3;
                }
                int base = 4 + (iv * 6 + j) * 4;
                params[base + 0] = (float)q0;
                params[base + 1] = (float)q1;
                params[base + 2] = (float)q2;
                params[base + 3] = (float)q3;
            }
        }
    }
}

__global__ void eval_kernel(const float* __restrict__ x,
                            const float* __restrict__ params,
                            float* __restrict__ out, int n) {
    __shared__ float4 sc4[18];  // 72 floats: [iv][j] -> float4 of coeffs
    if (threadIdx.x < 18)
        sc4[threadIdx.x] = reinterpret_cast<const float4*>(params + 4)[threadIdx.x];
    __syncthreads();
    const float xb1 = params[0], xb2 = params[1];

    int tid = blockIdx.x * blockDim.x + threadIdx.x;
    int stride = gridDim.x * blockDim.x;
    int nquad = n >> 2;
    const float4* x4 = reinterpret_cast<const float4*>(x);
    float4* out4 = reinterpret_cast<float4*>(out);

    for (int p = tid; p < nquad; p += stride) {
        float4 v = x4[p];
        float xs[4] = {v.x, v.y, v.z, v.w};
        float r[4][6];
#pragma unroll
        for (int q = 0; q < 4; ++q) {
            float xv = xs[q];
            int iv = (int)(xv >= xb1) + (int)(xv >= xb2);
            const float4* c4 = sc4 + iv * 6;
#pragma unroll
            for (int j = 0; j < 6; ++j) {
                float4 c = c4[j];
                r[q][j] = ((c.w * xv + c.z) * xv + c.y) * xv + c.x;
            }
        }
        float4* o = out4 + (size_t)p * 6;
        o[0] = make_float4(r[0][0], r[0][1], r[0][2], r[0][3]);
        o[1] = make_float4(r[0][4], r[0][5], r[1][0], r[1][1]);
        o[2] = make_float4(r[1][2], r[1][3], r[1][4], r[1][5]);
        o[3] = make_float4(r[2][0], r[2][1], r[2][2], r[2][3]);
        o[4] = make_float4(r[2][4], r[2][5], r[3][0], r[3][1]);
        o[5] = make_float4(r[3][2], r[3][3], r[3][4], r[3][5]);
    }
    // tail (n % 4 leftover points)
    if (tid < (n & 3)) {
        int i = (nquad << 2) + tid;
        float xv = x[i];
        int iv = (int)(xv >= xb1) + (int)(xv >= xb2);
        const float4* c4 = sc4 + iv * 6;
#pragma unroll
        for (int j = 0; j < 6; ++j) {
            float4 c = c4[j];
            out[(size_t)i * 6 + j] = ((c.w * xv + c.z) * xv + c.y) * xv + c.x;
        }
    }
}

extern "C" void kernel_launch(void* const* d_in, const int* in_sizes, int n_in,
                              void* d_out, int out_size, void* d_ws, size_t ws_size,
                              hipStream_t stream) {
    const float* x = (const float*)d_in[0];
    const float* knots = (const float*)d_in[1];
    float* out = (float*)d_out;
    int n = in_sizes[0];

    float* wsf = (float*)d_ws;
    float* params = wsf;                   // 128 floats reserved
    float* bmin = wsf + 128;               // RED_BLOCKS floats
    float* bmax = wsf + 128 + RED_BLOCKS;  // RED_BLOCKS floats

    reduce_minmax_kernel<<<RED_BLOCKS, RED_THREADS, 0, stream>>>(x, n, bmin, bmax);
    finalize_kernel<<<1, 256, 0, stream>>>(bmin, bmax, RED_BLOCKS, knots, params);
    eval_kernel<<<EVAL_BLOCKS, EVAL_THREADS, 0, stream>>>(x, params, out, n);
}

// Round 2
// 235.395 us; speedup vs baseline: 1.1029x; 1.1029x over previous
//
#include <hip/hip_runtime.h>
#include <math.h>

#define NKNOTS 10
#define RED_BLOCKS 1024
#define RED_THREADS 256
#define EVAL_BLOCKS 4096
#define EVAL_THREADS 256

// ws float layout:
//   [0]      xb1  (raw-x boundary equivalent to xn >= t[4])
//   [1]      xb2  (raw-x boundary equivalent to xn >= t[5])
//   [4..76)  72 composed cubic coeffs: [iv][basis j][k], k ascending powers of raw x
//   [128..128+RED_BLOCKS)               block mins
//   [128+RED_BLOCKS..128+2*RED_BLOCKS)  block maxs

__global__ void reduce_minmax_kernel(const float* __restrict__ x, int n,
                                     float* __restrict__ bmin,
                                     float* __restrict__ bmax) {
    float lmin = INFINITY, lmax = -INFINITY;
    int tid = blockIdx.x * blockDim.x + threadIdx.x;
    int stride = gridDim.x * blockDim.x;
    int n4 = n >> 2;
    const float4* x4 = reinterpret_cast<const float4*>(x);
    for (int i = tid; i < n4; i += stride) {
        float4 v = x4[i];
        lmin = fminf(lmin, fminf(fminf(v.x, v.y), fminf(v.z, v.w)));
        lmax = fmaxf(lmax, fmaxf(fmaxf(v.x, v.y), fmaxf(v.z, v.w)));
    }
    for (int i = (n4 << 2) + tid; i < n; i += stride) {
        float v = x[i];
        lmin = fminf(lmin, v);
        lmax = fmaxf(lmax, v);
    }
#pragma unroll
    for (int off = 32; off > 0; off >>= 1) {
        lmin = fminf(lmin, __shfl_down(lmin, off));
        lmax = fmaxf(lmax, __shfl_down(lmax, off));
    }
    __shared__ float smin[RED_THREADS / 64], smax[RED_THREADS / 64];
    int wave = threadIdx.x >> 6;
    if ((threadIdx.x & 63) == 0) { smin[wave] = lmin; smax[wave] = lmax; }
    __syncthreads();
    if (threadIdx.x == 0) {
        float m = smin[0], M = smax[0];
#pragma unroll
        for (int w = 1; w < RED_THREADS / 64; ++w) {
            m = fminf(m, smin[w]);
            M = fmaxf(M, smax[w]);
        }
        bmin[blockIdx.x] = m;
        bmax[blockIdx.x] = M;
    }
}

// Symbolically runs Cox-de Boor per non-degenerate interval, producing the 6
// basis cubics with the affine normalization xn = (x - xmin)/denom composed in.
__global__ void finalize_kernel(const float* __restrict__ bmin,
                                const float* __restrict__ bmax, int nb,
                                const float* __restrict__ knots,
                                float* __restrict__ params) {
    float lmin = INFINITY, lmax = -INFINITY;
    for (int i = threadIdx.x; i < nb; i += blockDim.x) {
        lmin = fminf(lmin, bmin[i]);
        lmax = fmaxf(lmax, bmax[i]);
    }
#pragma unroll
    for (int off = 32; off > 0; off >>= 1) {
        lmin = fminf(lmin, __shfl_down(lmin, off));
        lmax = fmaxf(lmax, __shfl_down(lmax, off));
    }
    __shared__ float smin[4], smax[4];
    int wave = threadIdx.x >> 6;
    if ((threadIdx.x & 63) == 0) { smin[wave] = lmin; smax[wave] = lmax; }
    __syncthreads();
    if (threadIdx.x == 0) {
        float m = smin[0], M = smax[0];
#pragma unroll
        for (int w = 1; w < 4; ++w) {
            m = fminf(m, smin[w]);
            M = fmaxf(M, smax[w]);
        }
        float denom_f = M - m + 1e-8f;   // f32 to match reference normalization
        double s = 1.0 / (double)denom_f;
        double bb = -(double)m * s;      // xn = s*x + bb
        double t[NKNOTS];
#pragma unroll
        for (int j = 0; j < NKNOTS; ++j) t[j] = (double)knots[j];

        // interval boundaries mapped back to raw x space
        params[0] = (float)((double)m + t[4] * (double)denom_f);
        params[1] = (float)((double)m + t[5] * (double)denom_f);

        for (int iv = 0; iv < 3; ++iv) {
            // B[j][k]: coeff of xn^k for basis level-d entry j
            double B[9][4];
            for (int j = 0; j < 9; ++j)
                for (int k = 0; k < 4; ++k) B[j][k] = 0.0;
            B[3 + iv][0] = 1.0;  // indicator of elementary interval [t[3+iv], t[4+iv])
            for (int d = 1; d <= 3; ++d) {
                for (int j = 0; j + d <= 8; ++j) {
                    double den1 = t[j + d] - t[j];
                    double den2 = t[j + d + 1] - t[j + 1];
                    double i1 = (den1 > 0.0) ? 1.0 / den1 : 0.0;
                    double i2 = (den2 > 0.0) ? 1.0 / den2 : 0.0;
                    // new B[j] = (xn - t[j])*i1*B[j] + (t[j+d+1] - xn)*i2*B[j+1]
                    double a1 = -t[j] * i1, b1 = i1;
                    double a2 = t[j + d + 1] * i2, b2 = -i2;
                    double nb0 = a1 * B[j][0] + a2 * B[j + 1][0];
                    double nb1 = a1 * B[j][1] + b1 * B[j][0] + a2 * B[j + 1][1] + b2 * B[j + 1][0];
                    double nb2 = a1 * B[j][2] + b1 * B[j][1] + a2 * B[j + 1][2] + b2 * B[j + 1][1];
                    double nb3 = a1 * B[j][3] + b1 * B[j][2] + a2 * B[j + 1][3] + b2 * B[j + 1][2];
                    B[j][0] = nb0; B[j][1] = nb1; B[j][2] = nb2; B[j][3] = nb3;
                }
            }
            // compose with xn = s*x + bb:  q(x) = P(s*x + bb) via symbolic Horner
            for (int j = 0; j < 6; ++j) {
                double q0 = B[j][3], q1 = 0.0, q2 = 0.0, q3 = 0.0;
                for (int k = 2; k >= 0; --k) {
                    double r0 = q0 * bb + B[j][k];
                    double r1 = q1 * bb + q0 * s;
                    double r2 = q2 * bb + q1 * s;
                    double r3 = q3 * bb + q2 * s;
                    q0 = r0; q1 = r1; q2 = r2; q3 = r3;
                }
                int base = 4 + (iv * 6 + j) * 4;
                params[base + 0] = (float)q0;
                params[base + 1] = (float)q1;
                params[base + 2] = (float)q2;
                params[base + 3] = (float)q3;
            }
        }
    }
}

__global__ void eval_kernel(const float* __restrict__ x,
                            const float* __restrict__ params,
                            float* __restrict__ out, int n) {
    __shared__ float4 sc4[18];                       // 72 coeff floats
    __shared__ float4 stage[EVAL_THREADS / 64][192]; // per-wave 3 KB staging
    if (threadIdx.x < 18)
        sc4[threadIdx.x] = reinterpret_cast<const float4*>(params + 4)[threadIdx.x];
    __syncthreads();
    const float xb1 = params[0], xb2 = params[1];

    const int lane = threadIdx.x & 63;
    const int wave = threadIdx.x >> 6;
    const int gwave = blockIdx.x * (blockDim.x >> 6) + wave;
    const int nwaves = gridDim.x * (blockDim.x >> 6);

    const int npair = n >> 1;            // point-pairs
    const int nblk = (npair + 63) >> 6;  // 64-pair blocks (one per wave-iter)
    const size_t nf4 = (size_t)npair * 3;
    const float2* x2 = reinterpret_cast<const float2*>(x);
    float4* out4 = reinterpret_cast<float4*>(out);
    float4* st = stage[wave];

    for (int blk = gwave; blk < nblk; blk += nwaves) {
        int p = (blk << 6) + lane;
        float4 s0, s1, s2;
        if (p < npair) {
            float2 v = x2[p];
            float ra[6], rb[6];
            {
                float xv = v.x;
                int iv = (int)(xv >= xb1) + (int)(xv >= xb2);
                const float4* c4 = sc4 + iv * 6;
#pragma unroll
                for (int j = 0; j < 6; ++j) {
                    float4 c = c4[j];
                    ra[j] = ((c.w * xv + c.z) * xv + c.y) * xv + c.x;
                }
            }
            {
                float xv = v.y;
                int iv = (int)(xv >= xb1) + (int)(xv >= xb2);
                const float4* c4 = sc4 + iv * 6;
#pragma unroll
                for (int j = 0; j < 6; ++j) {
                    float4 c = c4[j];
                    rb[j] = ((c.w * xv + c.z) * xv + c.y) * xv + c.x;
                }
            }
            s0 = make_float4(ra[0], ra[1], ra[2], ra[3]);
            s1 = make_float4(ra[4], ra[5], rb[0], rb[1]);
            s2 = make_float4(rb[2], rb[3], rb[4], rb[5]);
        } else {
            s0 = s1 = s2 = make_float4(0.f, 0.f, 0.f, 0.f);
        }
        // wave-private staging: lane-strided write, then coalesced read+store
        st[lane * 3 + 0] = s0;
        st[lane * 3 + 1] = s1;
        st[lane * 3 + 2] = s2;
        __builtin_amdgcn_wave_barrier();  // compile-time fence; wave is lockstep
        size_t f0 = (size_t)blk * 192;
#pragma unroll
        for (int k = 0; k < 3; ++k) {
            size_t f = f0 + (size_t)(k << 6) + lane;
            if (f < nf4) out4[f] = st[(k << 6) + lane];
        }
        __builtin_amdgcn_wave_barrier();  // keep next iter's writes behind reads
    }
    // odd-n tail: last point handled scalar
    if ((n & 1) && blockIdx.x == 0 && threadIdx.x == 0) {
        float xv = x[n - 1];
        int iv = (int)(xv >= xb1) + (int)(xv >= xb2);
        const float4* c4 = sc4 + iv * 6;
#pragma unroll
        for (int j = 0; j < 6; ++j) {
            float4 c = c4[j];
            out[(size_t)(n - 1) * 6 + j] = ((c.w * xv + c.z) * xv + c.y) * xv + c.x;
        }
    }
}

extern "C" void kernel_launch(void* const* d_in, const int* in_sizes, int n_in,
                              void* d_out, int out_size, void* d_ws, size_t ws_size,
                              hipStream_t stream) {
    const float* x = (const float*)d_in[0];
    const float* knots = (const float*)d_in[1];
    float* out = (float*)d_out;
    int n = in_sizes[0];

    float* wsf = (float*)d_ws;
    float* params = wsf;                   // 128 floats reserved
    float* bmin = wsf + 128;               // RED_BLOCKS floats
    float* bmax = wsf + 128 + RED_BLOCKS;  // RED_BLOCKS floats

    reduce_minmax_kernel<<<RED_BLOCKS, RED_THREADS, 0, stream>>>(x, n, bmin, bmax);
    finalize_kernel<<<1, 256, 0, stream>>>(bmin, bmax, RED_BLOCKS, knots, params);
    eval_kernel<<<EVAL_BLOCKS, EVAL_THREADS, 0, stream>>>(x, params, out, n);
}